// Round 5
// baseline (412.226 us; speedup 1.0000x reference)
//
#include <hip/hip_runtime.h>
#include <hip/hip_bf16.h>

// Problem constants (match reference setup_inputs)
constexpr int D     = 128;            // D_IN == D_OUT
constexpr int R1    = 17;             // NUM_REL + 1
constexpr int BATCH = 16384;
constexpr int S     = 32;             // NUM_SAMPLE
constexpr int K     = R1 * D;         // 2176 (GEMM K dim)
constexpr int KB    = K / 8;          // 272 k-blocks of 8
constexpr int NPB   = 8;              // nodes (M rows) per block, 1 per wave
constexpr int ASTR  = K + 4;          // agg row stride in dwords (pad 4 -> bank offset 4/row)
constexpr int THREADS = 512;

typedef __attribute__((ext_vector_type(8))) short short8;  // bf16x8 MFMA fragment
typedef __attribute__((ext_vector_type(4))) float f32x4;   // MFMA accumulator

__device__ __forceinline__ unsigned short f2bf_u(float f) {
    union { float f; unsigned u; } c; c.f = f;
    unsigned u = c.u;
    u += 0x7fffu + ((u >> 16) & 1u);
    return (unsigned short)(u >> 16);
}

// Pack W[17][128][128] (r,o,i) f32 -> Bp bf16 in B-fragment order:
// Bp[ot][kb][o][j]  where o_global = ot*16+o, k = kb*8+j, k = r*128+i.
__global__ void pack_w_kernel(const float* __restrict__ W, short* __restrict__ Bp) {
    int tid = blockIdx.x * 256 + threadIdx.x;
    if (tid >= R1 * D * D) return;
    int og = tid / K;            // 0..127 (output col)
    int k  = tid - og * K;       // 0..2175
    int r = k >> 7, i = k & 127;
    float v = W[((size_t)r * D + og) * D + i];
    int ot = og >> 4, o = og & 15, kb = k >> 3, j = k & 7;
    Bp[(((size_t)ot * KB + kb) * 16 + o) * 8 + j] = (short)f2bf_u(v);
}

__global__ __launch_bounds__(THREADS, 4)   // 4 waves/EU -> 2 blocks/CU (LDS-bound anyway)
void rgcn_kernel(const float* __restrict__ embed,   // [1e6][128] f32
                 const short* __restrict__ Bp,      // packed bf16 weights (d_ws)
                 const int*   __restrict__ nbrs,    // [16384][32]
                 const int*   __restrict__ rels,    // [16384][32]
                 float* __restrict__ out)           // [16384][128]
{
    __shared__ float aggf[NPB][ASTR];               // 8*2180*4 = 69,760 B -> 2 blocks/CU

    const int t     = threadIdx.x;
    const int lane  = t & 63;
    const int w     = t >> 6;                       // wave 0..7 -> node w
    const int node0 = blockIdx.x * NPB;
    const int gn    = node0 + w;

    // prefetch this wave's indices (latency hidden under LDS zero-init):
    // lanes 0..31 = neighbor ids, lanes 32..63 = relation ids
    int my;
    if (lane < 32) my = nbrs[(size_t)gn * S + lane];
    else           my = rels[(size_t)gn * S + (lane - 32)];

    // zero agg
    float* af = &aggf[0][0];
    for (int i = t; i < NPB * ASTR; i += THREADS) af[i] = 0.0f;
    __syncthreads();

    // ---------------- phase 1: gather + ds_add_f32 accumulate (branch-free) ----------
    // wave w owns node w; lane owns dims {2*lane, 2*lane+1}. Per sample:
    // coalesced float2 row-load (512B/wave) + 2 fire-and-forget LDS atomic adds.
    // No register accumulators, no branches -> loads stream continuously.
    {
        float* arow = &aggf[w][2 * lane];
        #pragma unroll
        for (int s = 0; s < S; ++s) {
            const int idx = __builtin_amdgcn_readlane(my, s);        // scalar
            const float2 v = *reinterpret_cast<const float2*>(
                embed + (size_t)idx * D + 2 * lane);
            const int r = __builtin_amdgcn_readlane(my, 32 + s);     // scalar
            float* p = arow + r * D;       // scalar offset + lane offset
            atomicAdd(p,     v.x);          // ds_add_f32 (no-return), 2-way bank = free
            atomicAdd(p + 1, v.y);
        }
    }
    __syncthreads();

    // ---------------- phase 2: C[8 x 128] = A[8 x 2176] @ B via bf16 MFMA ------------
    // wave w computes output cols [w*16, w*16+16). A-rows 8..15 duplicate rows 0..7
    // (same LDS addr -> broadcast); duplicate C-rows are simply not stored.
    {
        const int col = lane & 15;       // output col within tile / B fragment col
        const int kb4 = lane >> 4;       // k-subblock 0..3
        const int ar  = col & 7;         // A row (node), dup for col>=8

        f32x4 acc = {0.f, 0.f, 0.f, 0.f};

        const float* ap = &aggf[ar][kb4 * 8];
        const short* bb = Bp + (((size_t)w * KB + kb4) * 16 + col) * 8;

        #pragma unroll 4
        for (int step = 0; step < K / 32; ++step) {
            const float4 x = *reinterpret_cast<const float4*>(ap + step * 32);
            const float4 y = *reinterpret_cast<const float4*>(ap + step * 32 + 4);
            union { __hip_bfloat162 h[4]; short8 s; } u;
            u.h[0] = __float22bfloat162_rn(make_float2(x.x, x.y));
            u.h[1] = __float22bfloat162_rn(make_float2(x.z, x.w));
            u.h[2] = __float22bfloat162_rn(make_float2(y.x, y.y));
            u.h[3] = __float22bfloat162_rn(make_float2(y.z, y.w));
            const short8 b = *reinterpret_cast<const short8*>(bb + (size_t)step * 512);
            acc = __builtin_amdgcn_mfma_f32_16x16x32_bf16(u.s, b, acc, 0, 0, 0);
        }

        const float sc = 1000.0f / (float)(S * R1);
        #pragma unroll
        for (int j = 0; j < 4; ++j) {
            const int mrow = kb4 * 4 + j;            // C/D: row = (lane>>4)*4 + reg
            if (mrow < NPB)                          // store rows 0..7 only
                out[(size_t)(node0 + mrow) * D + w * 16 + col] = fmaxf(acc[j] * sc, 0.0f);
        }
    }
}

extern "C" void kernel_launch(void* const* d_in, const int* in_sizes, int n_in,
                              void* d_out, int out_size, void* d_ws, size_t ws_size,
                              hipStream_t stream) {
    const float* embed = (const float*)d_in[0];
    const float* W     = (const float*)d_in[1];
    const int*   nbrs  = (const int*)d_in[2];
    const int*   rels  = (const int*)d_in[3];
    float* out = (float*)d_out;
    short* Bp  = (short*)d_ws;   // 17*128*128*2 B = 557,056 B of scratch

    hipLaunchKernelGGL(pack_w_kernel, dim3((R1 * D * D + 255) / 256), dim3(256), 0, stream,
                       W, Bp);
    hipLaunchKernelGGL(rgcn_kernel, dim3(BATCH / NPB), dim3(THREADS), 0, stream,
                       embed, Bp, nbrs, rels, out);
}

// Round 6
// 138.045 us; speedup vs baseline: 2.9862x; 2.9862x over previous
//
#include <hip/hip_runtime.h>
#include <hip/hip_bf16.h>

// Problem constants (match reference setup_inputs)
constexpr int D     = 128;            // D_IN == D_OUT
constexpr int R1    = 17;             // NUM_REL + 1
constexpr int BATCH = 16384;
constexpr int S     = 32;             // NUM_SAMPLE
constexpr int K     = R1 * D;         // 2176 (GEMM K dim)
constexpr int KB    = K / 8;          // 272 k-blocks of 8

constexpr size_t BP_BYTES  = (size_t)R1 * D * D * 2;   // 557,056  (packed W)
constexpr size_t AGG_OFF   = BP_BYTES;                 // 16B-aligned
constexpr size_t AGG_BYTES = (size_t)BATCH * K * 2;    // 71,303,168 (bf16 agg)

typedef __attribute__((ext_vector_type(8))) short short8;  // bf16x8 MFMA fragment
typedef __attribute__((ext_vector_type(4))) float f32x4;   // MFMA accumulator

__device__ __forceinline__ unsigned short f2bf_u(float f) {
    union { float f; unsigned u; } c; c.f = f;
    unsigned u = c.u;
    u += 0x7fffu + ((u >> 16) & 1u);
    return (unsigned short)(u >> 16);
}
__device__ __forceinline__ unsigned pack2bf(float lo, float hi) {
    return (unsigned)f2bf_u(lo) | ((unsigned)f2bf_u(hi) << 16);
}

// Pack W[17][128][128] (r,o,i) f32 -> Bp bf16 in B-fragment order:
// Bp[ot][kb][o][j]  where o_global = ot*16+o, k = kb*8+j, k = r*128+i.
__global__ void pack_w_kernel(const float* __restrict__ W, short* __restrict__ Bp) {
    int tid = blockIdx.x * 256 + threadIdx.x;
    if (tid >= R1 * D * D) return;
    int og = tid / K;
    int k  = tid - og * K;
    int r = k >> 7, i = k & 127;
    float v = W[((size_t)r * D + og) * D + i];
    int ot = og >> 4, o = og & 15, kb = k >> 3, j = k & 7;
    Bp[(((size_t)ot * KB + kb) * 16 + o) * 8 + j] = (short)f2bf_u(v);
}

// wave-uniform relation r -> scalar branch cascade, adds x into acc[r]
#define ACC_SWITCH(r, x)                                              \
    switch (r) {                                                      \
        case 0:  a0.x  += x.x; a0.y  += x.y; break;                   \
        case 1:  a1.x  += x.x; a1.y  += x.y; break;                   \
        case 2:  a2.x  += x.x; a2.y  += x.y; break;                   \
        case 3:  a3.x  += x.x; a3.y  += x.y; break;                   \
        case 4:  a4.x  += x.x; a4.y  += x.y; break;                   \
        case 5:  a5.x  += x.x; a5.y  += x.y; break;                   \
        case 6:  a6.x  += x.x; a6.y  += x.y; break;                   \
        case 7:  a7.x  += x.x; a7.y  += x.y; break;                   \
        case 8:  a8.x  += x.x; a8.y  += x.y; break;                   \
        case 9:  a9.x  += x.x; a9.y  += x.y; break;                   \
        case 10: a10.x += x.x; a10.y += x.y; break;                   \
        case 11: a11.x += x.x; a11.y += x.y; break;                   \
        case 12: a12.x += x.x; a12.y += x.y; break;                   \
        case 13: a13.x += x.x; a13.y += x.y; break;                   \
        case 14: a14.x += x.x; a14.y += x.y; break;                   \
        case 15: a15.x += x.x; a15.y += x.y; break;                   \
        default: a16.x += x.x; a16.y += x.y; break;                   \
    }

// ---------------- Kernel A: gather + per-relation sum -> bf16 agg in d_ws ----------------
// No LDS; wave per node; lane owns dims {2*lane, 2*lane+1}. 4 chunks of
// {8 coalesced float2 row-loads, then 8 switch-accumulates}. VGPR ~72 ->
// high occupancy for gather latency hiding.
__global__ __launch_bounds__(256, 6)
void agg_kernel(const float* __restrict__ embed,   // [1e6][128] f32
                const int*   __restrict__ nbrs,    // [16384][32]
                const int*   __restrict__ rels,    // [16384][32]
                short*       __restrict__ Ag)      // [16384][2176] bf16
{
    const int t    = threadIdx.x;
    const int lane = t & 63;
    const int w    = t >> 6;                 // wave 0..3
    const int gn   = blockIdx.x * 4 + w;     // node

    // lanes 0..31 = neighbor ids, lanes 32..63 = relation ids
    int my;
    if (lane < 32) my = nbrs[(size_t)gn * S + lane];
    else           my = rels[(size_t)gn * S + (lane - 32)];

    float2 a0={0,0},a1={0,0},a2={0,0},a3={0,0},a4={0,0},a5={0,0},
           a6={0,0},a7={0,0},a8={0,0},a9={0,0},a10={0,0},a11={0,0},
           a12={0,0},a13={0,0},a14={0,0},a15={0,0},a16={0,0};

    #pragma unroll 1
    for (int c = 0; c < 4; ++c) {
        const int sbase = c * 8;
        float2 v[8];
        #pragma unroll
        for (int j = 0; j < 8; ++j) {
            const int idx = __builtin_amdgcn_readlane(my, sbase + j);     // SGPR
            v[j] = *reinterpret_cast<const float2*>(embed + (size_t)idx * D + 2 * lane);
        }
        #pragma unroll
        for (int j = 0; j < 8; ++j) {
            const int r = __builtin_amdgcn_readlane(my, 32 + sbase + j);  // SGPR
            const float2 x = v[j];
            ACC_SWITCH(r, x)
        }
    }

    // bf16x2 packed stores: dword index r*64+lane within the node's row
    unsigned* orow = reinterpret_cast<unsigned*>(Ag + (size_t)gn * K);
    orow[0*64+lane]  = pack2bf(a0.x,  a0.y);   orow[1*64+lane]  = pack2bf(a1.x,  a1.y);
    orow[2*64+lane]  = pack2bf(a2.x,  a2.y);   orow[3*64+lane]  = pack2bf(a3.x,  a3.y);
    orow[4*64+lane]  = pack2bf(a4.x,  a4.y);   orow[5*64+lane]  = pack2bf(a5.x,  a5.y);
    orow[6*64+lane]  = pack2bf(a6.x,  a6.y);   orow[7*64+lane]  = pack2bf(a7.x,  a7.y);
    orow[8*64+lane]  = pack2bf(a8.x,  a8.y);   orow[9*64+lane]  = pack2bf(a9.x,  a9.y);
    orow[10*64+lane] = pack2bf(a10.x, a10.y);  orow[11*64+lane] = pack2bf(a11.x, a11.y);
    orow[12*64+lane] = pack2bf(a12.x, a12.y);  orow[13*64+lane] = pack2bf(a13.x, a13.y);
    orow[14*64+lane] = pack2bf(a14.x, a14.y);  orow[15*64+lane] = pack2bf(a15.x, a15.y);
    orow[16*64+lane] = pack2bf(a16.x, a16.y);
}

// ---------------- Kernel B: C[16384x128] = Ag @ Bp (bf16 MFMA) ----------------
// M-tile 32; A staged once into LDS (padded stride); 8 waves x 16 cols x 2 m-steps.
constexpr int BM  = 32;
constexpr int AS2 = K + 8;   // LDS row stride in shorts (4368 B; bank offset 4/row)

__global__ __launch_bounds__(512, 1)
void gemm_kernel(const short* __restrict__ Ag,   // [16384][2176] bf16
                 const short* __restrict__ Bp,   // packed bf16 weights
                 float* __restrict__ out)        // [16384][128]
{
    __shared__ short At[BM][AS2];                // 32*4368 = 139,776 B

    const int t     = threadIdx.x;
    const int lane  = t & 63;
    const int w     = t >> 6;                    // wave 0..7
    const int node0 = blockIdx.x * BM;

    // stage: wave w copies rows w*4..w*4+3 (int4 = 8 bf16 per lane-op)
    #pragma unroll
    for (int rr = 0; rr < 4; ++rr) {
        const int row = w * 4 + rr;
        const int4* src = reinterpret_cast<const int4*>(Ag + (size_t)(node0 + row) * K);
        int4* dst = reinterpret_cast<int4*>(&At[row][0]);
        for (int c = lane; c < K / 8; c += 64)   // 272 int4 chunks per row
            dst[c] = src[c];
    }
    __syncthreads();

    const int m   = lane & 15;      // A row within m-tile / output col within tile
    const int kb4 = lane >> 4;      // k-subblock 0..3
    const short* bb = Bp + (((size_t)w * KB + kb4) * 16 + m) * 8;
    const float sc = 1000.0f / (float)(S * R1);

    #pragma unroll 1
    for (int ms = 0; ms < 2; ++ms) {
        const short* ar = &At[ms * 16 + m][kb4 * 8];
        f32x4 acc = {0.f, 0.f, 0.f, 0.f};
        #pragma unroll 4
        for (int step = 0; step < K / 32; ++step) {
            const short8 a = *reinterpret_cast<const short8*>(ar + step * 32);
            const short8 b = *reinterpret_cast<const short8*>(bb + (size_t)step * 512);
            acc = __builtin_amdgcn_mfma_f32_16x16x32_bf16(a, b, acc, 0, 0, 0);
        }
        #pragma unroll
        for (int j = 0; j < 4; ++j) {            // C/D: row = kb4*4+j, col = m
            out[(size_t)(node0 + ms * 16 + kb4 * 4 + j) * D + w * 16 + m] =
                fmaxf(acc[j] * sc, 0.0f);
        }
    }
}

// ---------------- Fallback: R4's fused kernel (used only if ws too small) ------------
constexpr int NPBF = 16;
constexpr int ASF  = K + 8;
__global__ __launch_bounds__(512, 4)
void rgcn_fused(const float* __restrict__ embed, const short* __restrict__ Bp,
                const int* __restrict__ nbrs, const int* __restrict__ rels,
                float* __restrict__ out)
{
    __shared__ short agg16[NPBF][ASF];
    const int t = threadIdx.x, lane = t & 63, w = t >> 6;
    const int node0 = blockIdx.x * NPBF;
    #pragma unroll 1
    for (int p = 0; p < 2; ++p) {
        const int nl = w * 2 + p;
        const int gn = node0 + nl;
        int my;
        if (lane < 32) my = nbrs[(size_t)gn * S + lane];
        else           my = rels[(size_t)gn * S + (lane - 32)];
        float2 a0={0,0},a1={0,0},a2={0,0},a3={0,0},a4={0,0},a5={0,0},
               a6={0,0},a7={0,0},a8={0,0},a9={0,0},a10={0,0},a11={0,0},
               a12={0,0},a13={0,0},a14={0,0},a15={0,0},a16={0,0};
        #pragma unroll 1
        for (int c = 0; c < 2; ++c) {
            const int sbase = c * 16;
            float2 v[16];
            #pragma unroll
            for (int j = 0; j < 16; ++j) {
                const int idx = __builtin_amdgcn_readlane(my, sbase + j);
                v[j] = *reinterpret_cast<const float2*>(embed + (size_t)idx * D + 2 * lane);
            }
            #pragma unroll
            for (int j = 0; j < 16; ++j) {
                const int r = __builtin_amdgcn_readlane(my, 32 + sbase + j);
                const float2 x = v[j];
                ACC_SWITCH(r, x)
            }
        }
        unsigned* arow = reinterpret_cast<unsigned*>(&agg16[nl][2 * lane]);
        arow[0*64]=pack2bf(a0.x,a0.y);   arow[1*64]=pack2bf(a1.x,a1.y);
        arow[2*64]=pack2bf(a2.x,a2.y);   arow[3*64]=pack2bf(a3.x,a3.y);
        arow[4*64]=pack2bf(a4.x,a4.y);   arow[5*64]=pack2bf(a5.x,a5.y);
        arow[6*64]=pack2bf(a6.x,a6.y);   arow[7*64]=pack2bf(a7.x,a7.y);
        arow[8*64]=pack2bf(a8.x,a8.y);   arow[9*64]=pack2bf(a9.x,a9.y);
        arow[10*64]=pack2bf(a10.x,a10.y);arow[11*64]=pack2bf(a11.x,a11.y);
        arow[12*64]=pack2bf(a12.x,a12.y);arow[13*64]=pack2bf(a13.x,a13.y);
        arow[14*64]=pack2bf(a14.x,a14.y);arow[15*64]=pack2bf(a15.x,a15.y);
        arow[16*64]=pack2bf(a16.x,a16.y);
    }
    __syncthreads();
    {
        const int m = lane & 15, kb4 = lane >> 4;
        f32x4 acc = {0.f,0.f,0.f,0.f};
        const short* ar = &agg16[m][kb4 * 8];
        const short* bb = Bp + (((size_t)w * KB + kb4) * 16 + m) * 8;
        #pragma unroll 4
        for (int step = 0; step < K / 32; ++step) {
            const short8 a = *reinterpret_cast<const short8*>(ar + step * 32);
            const short8 b = *reinterpret_cast<const short8*>(bb + (size_t)step * 512);
            acc = __builtin_amdgcn_mfma_f32_16x16x32_bf16(a, b, acc, 0, 0, 0);
        }
        const float sc = 1000.0f / (float)(S * R1);
        #pragma unroll
        for (int j = 0; j < 4; ++j)
            out[(size_t)(node0 + kb4 * 4 + j) * D + w * 16 + m] = fmaxf(acc[j] * sc, 0.0f);
    }
}

extern "C" void kernel_launch(void* const* d_in, const int* in_sizes, int n_in,
                              void* d_out, int out_size, void* d_ws, size_t ws_size,
                              hipStream_t stream) {
    const float* embed = (const float*)d_in[0];
    const float* W     = (const float*)d_in[1];
    const int*   nbrs  = (const int*)d_in[2];
    const int*   rels  = (const int*)d_in[3];
    float* out = (float*)d_out;
    short* Bp  = (short*)d_ws;

    hipLaunchKernelGGL(pack_w_kernel, dim3((R1 * D * D + 255) / 256), dim3(256), 0, stream,
                       W, Bp);

    if (ws_size >= AGG_OFF + AGG_BYTES) {
        short* Ag = (short*)((char*)d_ws + AGG_OFF);
        hipLaunchKernelGGL(agg_kernel, dim3(BATCH / 4), dim3(256), 0, stream,
                           embed, nbrs, rels, Ag);
        hipLaunchKernelGGL(gemm_kernel, dim3(BATCH / BM), dim3(512), 0, stream,
                           Ag, Bp, out);
    } else {
        hipLaunchKernelGGL(rgcn_fused, dim3(BATCH / NPBF), dim3(512), 0, stream,
                           embed, Bp, nbrs, rels, out);
    }
}

// Round 8
// 113.001 us; speedup vs baseline: 3.6480x; 1.2216x over previous
//
#include <hip/hip_runtime.h>
#include <hip/hip_bf16.h>

// Problem constants (match reference setup_inputs)
constexpr int D     = 128;            // D_IN == D_OUT
constexpr int R1    = 17;             // NUM_REL + 1
constexpr int BATCH = 16384;
constexpr int S     = 32;             // NUM_SAMPLE
constexpr int K     = R1 * D;         // 2176 (GEMM K dim)
constexpr int KB    = K / 8;          // 272 k-blocks of 8
constexpr int NPB   = 32;             // nodes (M rows) per block
constexpr int AS    = K + 8;          // agg row stride in shorts (4368 B, 16B-aligned)
constexpr int THREADS = 1024;         // 16 waves

typedef __attribute__((ext_vector_type(8))) short short8;  // bf16x8 MFMA fragment
typedef __attribute__((ext_vector_type(4))) float f32x4;   // MFMA accumulator

__device__ __forceinline__ unsigned short f2bf_u(float f) {
    union { float f; unsigned u; } c; c.f = f;
    unsigned u = c.u;
    u += 0x7fffu + ((u >> 16) & 1u);
    return (unsigned short)(u >> 16);
}
__device__ __forceinline__ unsigned pack2bf(float lo, float hi) {
    return (unsigned)f2bf_u(lo) | ((unsigned)f2bf_u(hi) << 16);
}

// Pack W[17][128][128] (r,o,i) f32 -> Bp bf16 in B-fragment order:
// Bp[ot][kb][o][j]  where o_global = ot*16+o, k = kb*8+j, k = r*128+i.
__global__ void pack_w_kernel(const float* __restrict__ W, short* __restrict__ Bp) {
    int tid = blockIdx.x * 256 + threadIdx.x;
    if (tid >= R1 * D * D) return;
    int og = tid / K;
    int k  = tid - og * K;
    int r = k >> 7, i = k & 127;
    float v = W[((size_t)r * D + og) * D + i];
    int ot = og >> 4, o = og & 15, kb = k >> 3, j = k & 7;
    Bp[(((size_t)ot * KB + kb) * 16 + o) * 8 + j] = (short)f2bf_u(v);
}

// wave-uniform relation rr_ -> scalar branch cascade, adds vv_ into named acc.
// NOTE: macro params must NOT be named 'x'/'y' (would capture member accesses).
#define ACC_SWITCH(rr_, vv_)                                          \
    switch (rr_) {                                                    \
        case 0:  a0.x  += vv_.x; a0.y  += vv_.y; break;               \
        case 1:  a1.x  += vv_.x; a1.y  += vv_.y; break;               \
        case 2:  a2.x  += vv_.x; a2.y  += vv_.y; break;               \
        case 3:  a3.x  += vv_.x; a3.y  += vv_.y; break;               \
        case 4:  a4.x  += vv_.x; a4.y  += vv_.y; break;               \
        case 5:  a5.x  += vv_.x; a5.y  += vv_.y; break;               \
        case 6:  a6.x  += vv_.x; a6.y  += vv_.y; break;               \
        case 7:  a7.x  += vv_.x; a7.y  += vv_.y; break;               \
        case 8:  a8.x  += vv_.x; a8.y  += vv_.y; break;               \
        case 9:  a9.x  += vv_.x; a9.y  += vv_.y; break;               \
        case 10: a10.x += vv_.x; a10.y += vv_.y; break;               \
        case 11: a11.x += vv_.x; a11.y += vv_.y; break;               \
        case 12: a12.x += vv_.x; a12.y += vv_.y; break;               \
        case 13: a13.x += vv_.x; a13.y += vv_.y; break;               \
        case 14: a14.x += vv_.x; a14.y += vv_.y; break;               \
        case 15: a15.x += vv_.x; a15.y += vv_.y; break;               \
        default: a16.x += vv_.x; a16.y += vv_.y; break;               \
    }

// issue 8 coalesced float2 row-loads for samples [sbase, sbase+8) of id-vec `myreg`
#define LOAD8(buf, myreg, sbase)                                                \
    { _Pragma("unroll") for (int j = 0; j < 8; ++j) {                           \
        const int idx_ = __builtin_amdgcn_readlane(myreg, (sbase) + j);         \
        buf[j] = *reinterpret_cast<const float2*>(                              \
            embed + (size_t)idx_ * D + 2 * lane); } }

// accumulate 8 samples from buf into the named accumulators
#define ACC8(myreg, sbase, buf)                                                 \
    { _Pragma("unroll") for (int j = 0; j < 8; ++j) {                           \
        const int rsel_ = __builtin_amdgcn_readlane(myreg, 32 + (sbase) + j);   \
        const float2 vsel_ = buf[j];                                            \
        ACC_SWITCH(rsel_, vsel_) } }

#define ZERO_ACC()                                                              \
    a0={0,0};a1={0,0};a2={0,0};a3={0,0};a4={0,0};a5={0,0};a6={0,0};a7={0,0};    \
    a8={0,0};a9={0,0};a10={0,0};a11={0,0};a12={0,0};a13={0,0};a14={0,0};        \
    a15={0,0};a16={0,0};

// pack accs to bf16x2 and store row nl (dword index r*64 + lane; 2-way bank = free)
#define STORE_ACC(nl)                                                           \
    { unsigned* arow_ = reinterpret_cast<unsigned*>(&At[nl][0]) + lane;         \
      arow_[0*64]=pack2bf(a0.x,a0.y);   arow_[1*64]=pack2bf(a1.x,a1.y);         \
      arow_[2*64]=pack2bf(a2.x,a2.y);   arow_[3*64]=pack2bf(a3.x,a3.y);         \
      arow_[4*64]=pack2bf(a4.x,a4.y);   arow_[5*64]=pack2bf(a5.x,a5.y);         \
      arow_[6*64]=pack2bf(a6.x,a6.y);   arow_[7*64]=pack2bf(a7.x,a7.y);         \
      arow_[8*64]=pack2bf(a8.x,a8.y);   arow_[9*64]=pack2bf(a9.x,a9.y);         \
      arow_[10*64]=pack2bf(a10.x,a10.y);arow_[11*64]=pack2bf(a11.x,a11.y);      \
      arow_[12*64]=pack2bf(a12.x,a12.y);arow_[13*64]=pack2bf(a13.x,a13.y);      \
      arow_[14*64]=pack2bf(a14.x,a14.y);arow_[15*64]=pack2bf(a15.x,a15.y);      \
      arow_[16*64]=pack2bf(a16.x,a16.y); }

__global__ __launch_bounds__(THREADS, 4)   // 4 waves/EU = the whole block; VGPR cap 128
void rgcn_kernel(const float* __restrict__ embed,   // [1e6][128] f32
                 const short* __restrict__ Bp,      // packed bf16 weights (d_ws)
                 const int*   __restrict__ nbrs,    // [16384][32]
                 const int*   __restrict__ rels,    // [16384][32]
                 float* __restrict__ out)           // [16384][128]
{
    __shared__ short At[NPB][AS];                   // 32*4368 = 139,776 B -> 1 block/CU

    const int t     = threadIdx.x;
    const int lane  = t & 63;
    const int w     = t >> 6;                       // wave 0..15
    const int node0 = blockIdx.x * NPB;

    // ---------------- phase 1: software-pipelined gather + register accumulate ----------
    // wave w owns nodes 2w, 2w+1; lane owns dims {2*lane, 2*lane+1}.
    // Straight-line double-buffered pipeline: >=8 loads always in flight.
    {
        const int gn0 = node0 + 2 * w;
        int my0, my1;
        if (lane < 32) {
            my0 = nbrs[(size_t)gn0 * S + lane];
            my1 = nbrs[(size_t)(gn0 + 1) * S + lane];
        } else {
            my0 = rels[(size_t)gn0 * S + (lane - 32)];
            my1 = rels[(size_t)(gn0 + 1) * S + (lane - 32)];
        }

        float2 a0,a1,a2,a3,a4,a5,a6,a7,a8,a9,a10,a11,a12,a13,a14,a15,a16;
        ZERO_ACC();
        float2 vA[8], vB[8];

        LOAD8(vA, my0, 0)          // node0 c0
        LOAD8(vB, my0, 8)          // node0 c1   (16 in flight)
        ACC8 (my0, 0,  vA)
        LOAD8(vA, my0, 16)         // node0 c2
        ACC8 (my0, 8,  vB)
        LOAD8(vB, my0, 24)         // node0 c3
        ACC8 (my0, 16, vA)
        LOAD8(vA, my1, 0)          // node1 c0 (prefetch across node boundary)
        ACC8 (my0, 24, vB)
        LOAD8(vB, my1, 8)          // node1 c1
        STORE_ACC(2 * w)
        ZERO_ACC();
        ACC8 (my1, 0,  vA)
        LOAD8(vA, my1, 16)         // node1 c2
        ACC8 (my1, 8,  vB)
        LOAD8(vB, my1, 24)         // node1 c3
        ACC8 (my1, 16, vA)
        ACC8 (my1, 24, vB)
        STORE_ACC(2 * w + 1)
    }
    __syncthreads();

    // ---------------- phase 2: C[32 x 128] = At[32 x 2176] @ Bp (bf16 MFMA) -------------
    // waves 0..7: wave w owns col-tile [w*16, w*16+16), both m-tiles (B-frag reused).
    if (w < 8) {
        const int m   = lane & 15;      // A row within m-tile / output col within tile
        const int kb4 = lane >> 4;      // k-subblock 0..3

        f32x4 acc0 = {0.f, 0.f, 0.f, 0.f};
        f32x4 acc1 = {0.f, 0.f, 0.f, 0.f};

        const short* ar0 = &At[m][kb4 * 8];
        const short* ar1 = &At[16 + m][kb4 * 8];
        const short* bb  = Bp + (((size_t)w * KB + kb4) * 16 + m) * 8;

        #pragma unroll 4
        for (int step = 0; step < K / 32; ++step) {
            const short8 b  = *reinterpret_cast<const short8*>(bb + (size_t)step * 512);
            const short8 x0 = *reinterpret_cast<const short8*>(ar0 + step * 32);
            const short8 x1 = *reinterpret_cast<const short8*>(ar1 + step * 32);
            acc0 = __builtin_amdgcn_mfma_f32_16x16x32_bf16(x0, b, acc0, 0, 0, 0);
            acc1 = __builtin_amdgcn_mfma_f32_16x16x32_bf16(x1, b, acc1, 0, 0, 0);
        }

        const float sc = 1000.0f / (float)(S * R1);
        #pragma unroll
        for (int j = 0; j < 4; ++j) {            // C/D: row = kb4*4+j, col = m
            const int mr = kb4 * 4 + j;
            out[(size_t)(node0 + mr) * D + w * 16 + m]      = fmaxf(acc0[j] * sc, 0.0f);
            out[(size_t)(node0 + 16 + mr) * D + w * 16 + m] = fmaxf(acc1[j] * sc, 0.0f);
        }
    }
}

extern "C" void kernel_launch(void* const* d_in, const int* in_sizes, int n_in,
                              void* d_out, int out_size, void* d_ws, size_t ws_size,
                              hipStream_t stream) {
    const float* embed = (const float*)d_in[0];
    const float* W     = (const float*)d_in[1];
    const int*   nbrs  = (const int*)d_in[2];
    const int*   rels  = (const int*)d_in[3];
    float* out = (float*)d_out;
    short* Bp  = (short*)d_ws;   // 557,056 B of scratch for packed W

    hipLaunchKernelGGL(pack_w_kernel, dim3((R1 * D * D + 255) / 256), dim3(256), 0, stream,
                       W, Bp);
    hipLaunchKernelGGL(rgcn_kernel, dim3(BATCH / NPB), dim3(THREADS), 0, stream,
                       embed, Bp, nbrs, rels, out);
}

// Round 9
// 105.435 us; speedup vs baseline: 3.9098x; 1.0718x over previous
//
#include <hip/hip_runtime.h>
#include <hip/hip_bf16.h>

// Problem constants (match reference setup_inputs)
constexpr int D     = 128;            // D_IN == D_OUT
constexpr int R1    = 17;             // NUM_REL + 1
constexpr int BATCH = 16384;
constexpr int S     = 32;             // NUM_SAMPLE
constexpr int K     = R1 * D;         // 2176 (GEMM K dim)
constexpr int KB    = K / 8;          // 272 k-blocks of 8
constexpr int NPB   = 16;             // nodes (M rows) per block
constexpr int AS    = K + 8;          // agg row stride in shorts (4368 B, 16B-aligned)
constexpr int THREADS = 512;          // 8 waves

typedef __attribute__((ext_vector_type(8))) short short8;  // bf16x8 MFMA fragment
typedef __attribute__((ext_vector_type(4))) float f32x4;   // MFMA accumulator

__device__ __forceinline__ unsigned short f2bf_u(float f) {
    union { float f; unsigned u; } c; c.f = f;
    unsigned u = c.u;
    u += 0x7fffu + ((u >> 16) & 1u);
    return (unsigned short)(u >> 16);
}
__device__ __forceinline__ unsigned pack2bf(float lo, float hi) {
    return (unsigned)f2bf_u(lo) | ((unsigned)f2bf_u(hi) << 16);
}

// Pack W[17][128][128] (r,o,i) f32 -> Bp bf16 in B-fragment order:
// Bp[ot][kb][o][j]  where o_global = ot*16+o, k = kb*8+j, k = r*128+i.
__global__ void pack_w_kernel(const float* __restrict__ W, short* __restrict__ Bp) {
    int tid = blockIdx.x * 256 + threadIdx.x;
    if (tid >= R1 * D * D) return;
    int og = tid / K;
    int k  = tid - og * K;
    int r = k >> 7, i = k & 127;
    float v = W[((size_t)r * D + og) * D + i];
    int ot = og >> 4, o = og & 15, kb = k >> 3, j = k & 7;
    Bp[(((size_t)ot * KB + kb) * 16 + o) * 8 + j] = (short)f2bf_u(v);
}

// wave-uniform relation rr_ -> scalar branch cascade, adds vv_ into named acc.
// NOTE: macro params must NOT be named 'x'/'y' (would capture member accesses).
#define ACC_SWITCH(rr_, vv_)                                          \
    switch (rr_) {                                                    \
        case 0:  a0.x  += vv_.x; a0.y  += vv_.y; break;               \
        case 1:  a1.x  += vv_.x; a1.y  += vv_.y; break;               \
        case 2:  a2.x  += vv_.x; a2.y  += vv_.y; break;               \
        case 3:  a3.x  += vv_.x; a3.y  += vv_.y; break;               \
        case 4:  a4.x  += vv_.x; a4.y  += vv_.y; break;               \
        case 5:  a5.x  += vv_.x; a5.y  += vv_.y; break;               \
        case 6:  a6.x  += vv_.x; a6.y  += vv_.y; break;               \
        case 7:  a7.x  += vv_.x; a7.y  += vv_.y; break;               \
        case 8:  a8.x  += vv_.x; a8.y  += vv_.y; break;               \
        case 9:  a9.x  += vv_.x; a9.y  += vv_.y; break;               \
        case 10: a10.x += vv_.x; a10.y += vv_.y; break;               \
        case 11: a11.x += vv_.x; a11.y += vv_.y; break;               \
        case 12: a12.x += vv_.x; a12.y += vv_.y; break;               \
        case 13: a13.x += vv_.x; a13.y += vv_.y; break;               \
        case 14: a14.x += vv_.x; a14.y += vv_.y; break;               \
        case 15: a15.x += vv_.x; a15.y += vv_.y; break;               \
        default: a16.x += vv_.x; a16.y += vv_.y; break;               \
    }

// issue 8 coalesced float2 row-loads for samples [sbase, sbase+8) of id-vec `myreg`
#define LOAD8(buf, myreg, sbase)                                                \
    { _Pragma("unroll") for (int j = 0; j < 8; ++j) {                           \
        const int idx_ = __builtin_amdgcn_readlane(myreg, (sbase) + j);         \
        buf[j] = *reinterpret_cast<const float2*>(                              \
            embed + (size_t)idx_ * D + 2 * lane); } }

// accumulate 8 samples from buf into the named accumulators
#define ACC8(myreg, sbase, buf)                                                 \
    { _Pragma("unroll") for (int j = 0; j < 8; ++j) {                           \
        const int rsel_ = __builtin_amdgcn_readlane(myreg, 32 + (sbase) + j);   \
        const float2 vsel_ = buf[j];                                            \
        ACC_SWITCH(rsel_, vsel_) } }

#define ZERO_ACC()                                                              \
    a0={0,0};a1={0,0};a2={0,0};a3={0,0};a4={0,0};a5={0,0};a6={0,0};a7={0,0};    \
    a8={0,0};a9={0,0};a10={0,0};a11={0,0};a12={0,0};a13={0,0};a14={0,0};        \
    a15={0,0};a16={0,0};

// pack accs to bf16x2 and store row nl (dword index r*64 + lane; 2-way bank = free)
#define STORE_ACC(nl)                                                           \
    { unsigned* arow_ = reinterpret_cast<unsigned*>(&At[nl][0]) + lane;         \
      arow_[0*64]=pack2bf(a0.x,a0.y);   arow_[1*64]=pack2bf(a1.x,a1.y);         \
      arow_[2*64]=pack2bf(a2.x,a2.y);   arow_[3*64]=pack2bf(a3.x,a3.y);         \
      arow_[4*64]=pack2bf(a4.x,a4.y);   arow_[5*64]=pack2bf(a5.x,a5.y);         \
      arow_[6*64]=pack2bf(a6.x,a6.y);   arow_[7*64]=pack2bf(a7.x,a7.y);         \
      arow_[8*64]=pack2bf(a8.x,a8.y);   arow_[9*64]=pack2bf(a9.x,a9.y);         \
      arow_[10*64]=pack2bf(a10.x,a10.y);arow_[11*64]=pack2bf(a11.x,a11.y);      \
      arow_[12*64]=pack2bf(a12.x,a12.y);arow_[13*64]=pack2bf(a13.x,a13.y);      \
      arow_[14*64]=pack2bf(a14.x,a14.y);arow_[15*64]=pack2bf(a15.x,a15.y);      \
      arow_[16*64]=pack2bf(a16.x,a16.y); }

__global__ __launch_bounds__(THREADS, 4)   // 4 waves/EU -> 2 blocks/CU; VGPR cap 128
void rgcn_kernel(const float* __restrict__ embed,   // [1e6][128] f32
                 const short* __restrict__ Bp,      // packed bf16 weights (d_ws)
                 const int*   __restrict__ nbrs,    // [16384][32]
                 const int*   __restrict__ rels,    // [16384][32]
                 float* __restrict__ out)           // [16384][128]
{
    __shared__ short At[NPB][AS];                   // 16*4368 = 69,888 B -> 2 blocks/CU

    const int t     = threadIdx.x;
    const int lane  = t & 63;
    const int w     = t >> 6;                       // wave 0..7
    const int node0 = blockIdx.x * NPB;

    // ---------------- phase 1: software-pipelined gather + register accumulate ----------
    // wave w owns nodes 2w, 2w+1; lane owns dims {2*lane, 2*lane+1}.
    // Straight-line double-buffered pipeline: >=8 loads always in flight,
    // including across the node boundary.
    {
        const int gn0 = node0 + 2 * w;
        int my0, my1;
        if (lane < 32) {
            my0 = nbrs[(size_t)gn0 * S + lane];
            my1 = nbrs[(size_t)(gn0 + 1) * S + lane];
        } else {
            my0 = rels[(size_t)gn0 * S + (lane - 32)];
            my1 = rels[(size_t)(gn0 + 1) * S + (lane - 32)];
        }

        float2 a0,a1,a2,a3,a4,a5,a6,a7,a8,a9,a10,a11,a12,a13,a14,a15,a16;
        ZERO_ACC();
        float2 vA[8], vB[8];

        LOAD8(vA, my0, 0)          // node0 c0
        LOAD8(vB, my0, 8)          // node0 c1   (16 in flight)
        ACC8 (my0, 0,  vA)
        LOAD8(vA, my0, 16)         // node0 c2
        ACC8 (my0, 8,  vB)
        LOAD8(vB, my0, 24)         // node0 c3
        ACC8 (my0, 16, vA)
        LOAD8(vA, my1, 0)          // node1 c0 (prefetch across node boundary)
        ACC8 (my0, 24, vB)
        LOAD8(vB, my1, 8)          // node1 c1
        STORE_ACC(2 * w)
        ZERO_ACC();
        ACC8 (my1, 0,  vA)
        LOAD8(vA, my1, 16)         // node1 c2
        ACC8 (my1, 8,  vB)
        LOAD8(vB, my1, 24)         // node1 c3
        ACC8 (my1, 16, vA)
        ACC8 (my1, 24, vB)
        STORE_ACC(2 * w + 1)
    }
    __syncthreads();

    // ---------------- phase 2: C[16 x 128] = At[16 x 2176] @ Bp (bf16 MFMA) -------------
    // wave w owns output col-tile [w*16, w*16+16) for all 16 rows.
    {
        const int m   = lane & 15;      // A row within m-tile / output col within tile
        const int kb4 = lane >> 4;      // k-subblock 0..3

        f32x4 acc = {0.f, 0.f, 0.f, 0.f};

        const short* ar = &At[m][kb4 * 8];
        const short* bb = Bp + (((size_t)w * KB + kb4) * 16 + m) * 8;

        #pragma unroll 4
        for (int step = 0; step < K / 32; ++step) {
            const short8 a = *reinterpret_cast<const short8*>(ar + step * 32);
            const short8 b = *reinterpret_cast<const short8*>(bb + (size_t)step * 512);
            acc = __builtin_amdgcn_mfma_f32_16x16x32_bf16(a, b, acc, 0, 0, 0);
        }

        const float sc = 1000.0f / (float)(S * R1);
        #pragma unroll
        for (int j = 0; j < 4; ++j) {            // C/D: row = kb4*4+j, col = m
            out[(size_t)(node0 + kb4 * 4 + j) * D + w * 16 + m] = fmaxf(acc[j] * sc, 0.0f);
        }
    }
}

extern "C" void kernel_launch(void* const* d_in, const int* in_sizes, int n_in,
                              void* d_out, int out_size, void* d_ws, size_t ws_size,
                              hipStream_t stream) {
    const float* embed = (const float*)d_in[0];
    const float* W     = (const float*)d_in[1];
    const int*   nbrs  = (const int*)d_in[2];
    const int*   rels  = (const int*)d_in[3];
    float* out = (float*)d_out;
    short* Bp  = (short*)d_ws;   // 557,056 B of scratch for packed W

    hipLaunchKernelGGL(pack_w_kernel, dim3((R1 * D * D + 255) / 256), dim3(256), 0, stream,
                       W, Bp);
    hipLaunchKernelGGL(rgcn_kernel, dim3(BATCH / NPB), dim3(THREADS), 0, stream,
                       embed, Bp, nbrs, rels, out);
}

// Round 10
// 97.499 us; speedup vs baseline: 4.2280x; 1.0814x over previous
//
#include <hip/hip_runtime.h>

// Problem constants (match reference setup_inputs)
constexpr int D     = 128;            // D_IN == D_OUT
constexpr int R1    = 17;             // NUM_REL + 1
constexpr int BATCH = 16384;
constexpr int S     = 32;             // NUM_SAMPLE
constexpr int K     = R1 * D;         // 2176 (GEMM K dim)
constexpr int KB    = K / 8;          // 272 k-blocks of 8
constexpr int NPB   = 16;             // nodes per group (one LDS buffer)
constexpr int NGRP  = 4;              // groups per block
constexpr int AS    = K + 8;          // agg row stride in shorts (4368 B -> bank offset 4/row)
constexpr int THREADS = 1024;         // 16 waves: 8 producers + 8 consumers
constexpr int GRID  = BATCH / (NPB * NGRP);   // 256 blocks (1 per CU)

typedef __attribute__((ext_vector_type(8))) short short8;  // bf16x8 MFMA fragment
typedef __attribute__((ext_vector_type(4))) float f32x4;   // MFMA accumulator

__device__ __forceinline__ unsigned short f2bf_u(float f) {
    union { float f; unsigned u; } c; c.f = f;
    unsigned u = c.u;
    u += 0x7fffu + ((u >> 16) & 1u);
    return (unsigned short)(u >> 16);
}
__device__ __forceinline__ unsigned pack2bf(float lo, float hi) {
    return (unsigned)f2bf_u(lo) | ((unsigned)f2bf_u(hi) << 16);
}

// Pack W[17][128][128] (r,o,i) f32 -> Bp bf16 in B-fragment order:
// Bp[ot][kb][o][j]  where o_global = ot*16+o, k = kb*8+j, k = r*128+i.
__global__ void pack_w_kernel(const float* __restrict__ W, short* __restrict__ Bp) {
    int tid = blockIdx.x * 256 + threadIdx.x;
    if (tid >= R1 * D * D) return;
    int og = tid / K;
    int k  = tid - og * K;
    int r = k >> 7, i = k & 127;
    float v = W[((size_t)r * D + og) * D + i];
    int ot = og >> 4, o = og & 15, kb = k >> 3, j = k & 7;
    Bp[(((size_t)ot * KB + kb) * 16 + o) * 8 + j] = (short)f2bf_u(v);
}

// wave-uniform relation rr_ -> scalar branch cascade, adds vv_ into named acc.
// NOTE: macro params must NOT be named 'x'/'y' (member-access capture; R7 lesson).
#define ACC_SWITCH(rr_, vv_)                                          \
    switch (rr_) {                                                    \
        case 0:  a0.x  += vv_.x; a0.y  += vv_.y; break;               \
        case 1:  a1.x  += vv_.x; a1.y  += vv_.y; break;               \
        case 2:  a2.x  += vv_.x; a2.y  += vv_.y; break;               \
        case 3:  a3.x  += vv_.x; a3.y  += vv_.y; break;               \
        case 4:  a4.x  += vv_.x; a4.y  += vv_.y; break;               \
        case 5:  a5.x  += vv_.x; a5.y  += vv_.y; break;               \
        case 6:  a6.x  += vv_.x; a6.y  += vv_.y; break;               \
        case 7:  a7.x  += vv_.x; a7.y  += vv_.y; break;               \
        case 8:  a8.x  += vv_.x; a8.y  += vv_.y; break;               \
        case 9:  a9.x  += vv_.x; a9.y  += vv_.y; break;               \
        case 10: a10.x += vv_.x; a10.y += vv_.y; break;               \
        case 11: a11.x += vv_.x; a11.y += vv_.y; break;               \
        case 12: a12.x += vv_.x; a12.y += vv_.y; break;               \
        case 13: a13.x += vv_.x; a13.y += vv_.y; break;               \
        case 14: a14.x += vv_.x; a14.y += vv_.y; break;               \
        case 15: a15.x += vv_.x; a15.y += vv_.y; break;               \
        default: a16.x += vv_.x; a16.y += vv_.y; break;               \
    }

// Gather + per-relation accumulate for ONE node into LDS row `row`.
// R4's proven schedule: 2 chunks of {16 coalesced float2 loads, 16 accumulates}.
__device__ __forceinline__ void gather_one(const float* __restrict__ embed,
                                           const int*   __restrict__ nbrs,
                                           const int*   __restrict__ rels,
                                           int gn, int lane, short* row)
{
    // lanes 0..31 = neighbor ids, lanes 32..63 = relation ids
    int my;
    if (lane < 32) my = nbrs[(size_t)gn * S + lane];
    else           my = rels[(size_t)gn * S + (lane - 32)];

    float2 a0={0,0},a1={0,0},a2={0,0},a3={0,0},a4={0,0},a5={0,0},
           a6={0,0},a7={0,0},a8={0,0},a9={0,0},a10={0,0},a11={0,0},
           a12={0,0},a13={0,0},a14={0,0},a15={0,0},a16={0,0};

    #pragma unroll 1
    for (int c = 0; c < 2; ++c) {
        const int sbase = c * 16;
        float2 v[16];
        #pragma unroll
        for (int j = 0; j < 16; ++j) {
            const int idx = __builtin_amdgcn_readlane(my, sbase + j);      // SGPR
            v[j] = *reinterpret_cast<const float2*>(embed + (size_t)idx * D + 2 * lane);
        }
        #pragma unroll
        for (int j = 0; j < 16; ++j) {
            const int r = __builtin_amdgcn_readlane(my, 32 + sbase + j);   // SGPR
            const float2 vx = v[j];
            ACC_SWITCH(r, vx)
        }
    }

    // packed bf16x2 stores: dword index r*64 + lane (lane-consecutive, conflict-free)
    unsigned* arow_ = reinterpret_cast<unsigned*>(row) + lane;
    arow_[0*64]  = pack2bf(a0.x,  a0.y);   arow_[1*64]  = pack2bf(a1.x,  a1.y);
    arow_[2*64]  = pack2bf(a2.x,  a2.y);   arow_[3*64]  = pack2bf(a3.x,  a3.y);
    arow_[4*64]  = pack2bf(a4.x,  a4.y);   arow_[5*64]  = pack2bf(a5.x,  a5.y);
    arow_[6*64]  = pack2bf(a6.x,  a6.y);   arow_[7*64]  = pack2bf(a7.x,  a7.y);
    arow_[8*64]  = pack2bf(a8.x,  a8.y);   arow_[9*64]  = pack2bf(a9.x,  a9.y);
    arow_[10*64] = pack2bf(a10.x, a10.y);  arow_[11*64] = pack2bf(a11.x, a11.y);
    arow_[12*64] = pack2bf(a12.x, a12.y);  arow_[13*64] = pack2bf(a13.x, a13.y);
    arow_[14*64] = pack2bf(a14.x, a14.y);  arow_[15*64] = pack2bf(a15.x, a15.y);
    arow_[16*64] = pack2bf(a16.x, a16.y);
}

// Producer-consumer fused kernel: waves 0..7 gather group g+1 into buf[(g+1)&1]
// while waves 8..15 run MFMA + C-write on group g from buf[g&1]. The HBM-bound
// gather runs continuously; the L2-bound B-stream and MFMA hide under it.
__global__ __launch_bounds__(THREADS, 4)   // 4 waves/EU; VGPR cap 128
void rgcn_pc_kernel(const float* __restrict__ embed,   // [1e6][128] f32
                    const short* __restrict__ Bp,      // packed bf16 weights (d_ws)
                    const int*   __restrict__ nbrs,    // [16384][32]
                    const int*   __restrict__ rels,    // [16384][32]
                    float* __restrict__ out)           // [16384][128]
{
    __shared__ short At[2][NPB][AS];                   // 2*16*2184*2 = 139,776 B

    const int t     = threadIdx.x;
    const int lane  = t & 63;
    const int w     = t >> 6;                          // wave 0..15
    const int base0 = blockIdx.x * NGRP * NPB;

    // prologue: producers fill buffer 0 with group 0
    if (w < 8) {
        #pragma unroll 1
        for (int p = 0; p < 2; ++p)
            gather_one(embed, nbrs, rels, base0 + 2 * w + p, lane, &At[0][2 * w + p][0]);
    }
    __syncthreads();

    #pragma unroll 1
    for (int g = 0; g < NGRP; ++g) {
        if (w < 8) {
            // ---- producers: gather group g+1 into the other buffer ----
            if (g + 1 < NGRP) {
                const int nb = base0 + (g + 1) * NPB;
                #pragma unroll 1
                for (int p = 0; p < 2; ++p)
                    gather_one(embed, nbrs, rels, nb + 2 * w + p, lane,
                               &At[(g + 1) & 1][2 * w + p][0]);
            }
        } else {
            // ---- consumers: C[16 x 128] = At[g&1] @ Bp for group g ----
            const int cw  = w - 8;          // col-tile 0..7
            const int m   = lane & 15;      // A row / output col within tile
            const int kb4 = lane >> 4;      // k-subblock 0..3

            f32x4 acc = {0.f, 0.f, 0.f, 0.f};
            const short* ar = &At[g & 1][m][kb4 * 8];
            const short* bb = Bp + (((size_t)cw * KB + kb4) * 16 + m) * 8;

            #pragma unroll 4
            for (int step = 0; step < K / 32; ++step) {
                const short8 a = *reinterpret_cast<const short8*>(ar + step * 32);
                const short8 b = *reinterpret_cast<const short8*>(bb + (size_t)step * 512);
                acc = __builtin_amdgcn_mfma_f32_16x16x32_bf16(a, b, acc, 0, 0, 0);
            }

            const float sc = 1000.0f / (float)(S * R1);
            const int nbase = base0 + g * NPB;
            #pragma unroll
            for (int j = 0; j < 4; ++j) {            // C/D: row = kb4*4+j, col = m
                out[(size_t)(nbase + kb4 * 4 + j) * D + cw * 16 + m] =
                    fmaxf(acc[j] * sc, 0.0f);
            }
        }
        __syncthreads();
    }
}

extern "C" void kernel_launch(void* const* d_in, const int* in_sizes, int n_in,
                              void* d_out, int out_size, void* d_ws, size_t ws_size,
                              hipStream_t stream) {
    const float* embed = (const float*)d_in[0];
    const float* W     = (const float*)d_in[1];
    const int*   nbrs  = (const int*)d_in[2];
    const int*   rels  = (const int*)d_in[3];
    float* out = (float*)d_out;
    short* Bp  = (short*)d_ws;   // 557,056 B of scratch for packed W

    hipLaunchKernelGGL(pack_w_kernel, dim3((R1 * D * D + 255) / 256), dim3(256), 0, stream,
                       W, Bp);
    hipLaunchKernelGGL(rgcn_pc_kernel, dim3(GRID), dim3(THREADS), 0, stream,
                       embed, Bp, nbrs, rels, out);
}